// Round 5
// baseline (338.470 us; speedup 1.0000x reference)
//
#include <hip/hip_runtime.h>
#include <math.h>

#define BB   2
#define SC   384
#define SH   112
#define SW   112
#define GH   224
#define GW   224
#define HWs  (SH*SW)     // 12544
#define HWg  (GH*GW)     // 50176
#define GT   22          // 16 + 2*3 guidance tile dim
#define NCB  2           // channel blocks
#define CPB  (SC/NCB)    // 192 channels per block

typedef float f32x2 __attribute__((ext_vector_type(2)));

__device__ __forceinline__ int reflect224(int v){
    v = v < 0 ? -v : v;
    v = v > 223 ? 446 - v : v;
    return v;
}

__launch_bounds__(256, 2)
__global__ void jbu_kernel(const float* __restrict__ src,
                           const float* __restrict__ gdn,
                           const float* __restrict__ sigs,
                           const float* __restrict__ sigr,
                           float* __restrict__ out)
{
    // LDS: 22*22*3*4 = 5808 B + 25*256*4 = 25600 B + 1024 B  => ~32.4 KB
    __shared__ float gtile[GT*GT*3];
    __shared__ float slab[25*256];
    __shared__ float invs_sh[256];

    const int bx = blockIdx.x;
    const int cb = bx / 392;             // 0..NCB-1
    const int r  = bx - cb*392;
    const int b  = r / 196;
    const int t  = r - b*196;
    const int th = t / 14, tw = t - th*14;
    const int h0 = th*16, w0 = tw*16;

    const int tid = threadIdx.x;

    const float ssv  = fabsf(sigs[0]);
    const float srv  = fabsf(sigr[0]);
    const float i2ss = 0.5f/(ssv*ssv);
    const float i2sr = 0.5f/(srv*srv);

    // zero the weight slab
    #pragma unroll
    for (int k=0;k<25;k++) slab[k*256+tid] = 0.f;

    // stage L2-normalized guidance tile, reflect applied at staging
    const float* gb = gdn + (size_t)b*3*HWg;
    for (int idx = tid; idx < GT*GT; idx += 256){
        int ty = idx / GT, tx = idx - ty*GT;
        int y = reflect224(h0 - 3 + ty);
        int x = reflect224(w0 - 3 + tx);
        float g0 = gb[y*GW + x];
        float g1 = gb[HWg   + y*GW + x];
        float g2 = gb[2*HWg + y*GW + x];
        float nrm = sqrtf(g0*g0 + g1*g1 + g2*g2);
        float inv = 1.0f / fmaxf(nrm, 1e-12f);
        gtile[idx*3+0] = g0*inv;
        gtile[idx*3+1] = g1*inv;
        gtile[idx*3+2] = g2*inv;
    }
    __syncthreads();

    // ---- phase 1: per-pixel effective 5x5 source weights ----
    // Fold the x2 bilinear upsample (half-pixel centers) into the 49 bilateral
    // taps; all contributions land in the 5x5 src window around (h>>1, w>>1).
    const int hh = tid >> 4, ww = tid & 15;
    const int h = h0 + hh, w = w0 + ww;
    const float c0 = gtile[((hh+3)*GT + (ww+3))*3 + 0];
    const float c1 = gtile[((hh+3)*GT + (ww+3))*3 + 1];
    const float c2 = gtile[((hh+3)*GT + (ww+3))*3 + 2];

    float wc0a[7]; int dc0a[7];
    #pragma unroll
    for (int j=0;j<7;j++){
        int xr = reflect224(w + j - 3);
        int a  = xr >> 1;
        int cs0 = a - 1 + (xr & 1);          // first src col of bilinear pair
        wc0a[j] = (xr & 1) ? 0.75f : 0.25f;  // its weight; second gets 1-w
        dc0a[j] = cs0 - ((w>>1) - 2);        // window slot, in [0,3]
    }

    float sum = 0.f;
    #pragma unroll
    for (int i=0;i<7;i++){
        int yr = reflect224(h + i - 3);
        int a  = yr >> 1;
        int rs0 = a - 1 + (yr & 1);
        float wr0 = (yr & 1) ? 0.75f : 0.25f;
        int dr0 = rs0 - ((h>>1) - 2);        // row slot, in [0,3]
        const float* grow = &gtile[((hh+i)*GT + ww)*3];
        float di2 = (float)((i-3)*(i-3));
        #pragma unroll
        for (int j=0;j<7;j++){
            float dot = c0*grow[j*3+0] + c1*grow[j*3+1] + c2*grow[j*3+2];
            float t2  = 2.0f - dot;
            float dj2 = (float)((j-3)*(j-3));
            float ck  = __expf(-(t2*t2*i2sr + (di2+dj2)*i2ss));
            sum += ck;
            float p0 = ck*wr0, p1 = ck - p0;
            float wc0 = wc0a[j];
            float q00 = p0*wc0, q01 = p0 - q00;
            float q10 = p1*wc0, q11 = p1 - q10;
            int base = (dr0*5 + dc0a[j])*256 + tid;   // column [tid] thread-exclusive
            slab[base        ] += q00;
            slab[base +   256] += q01;
            slab[base + 5*256] += q10;
            slab[base + 6*256] += q11;
        }
    }
    invs_sh[tid] = 1.0f / fmaxf(sum, 1e-7f);
    __syncthreads();

    // ---- phase 2: adaptive 5x5 conv over all channels ----
    const int wid  = tid >> 6, lane = tid & 63;
    const int wm   = lane >> 3, wn = lane & 7;
    const int m    = th*8 + wm, n = tw*8 + wn;   // shared src window (2x2 out px)

    // 2x2-pixel-group effective weights -> registers. The inline-asm tie
    // PINS each value in a VGPR: without it the compiler rematerializes
    // these LDS reads inside the channel loop (round-4 profile: VGPR=88,
    // ~4800 ds_reads/thread, 8-way bank conflicts, LDS-pipe-bound 196us).
    float wf[4][25];
    #pragma unroll
    for (int q=0;q<4;q++){
        int e = q>>1, f = q&1;
        int px = (2*wm+e)*16 + (2*wn+f);
        float inv = invs_sh[px];
        #pragma unroll
        for (int k=0;k<25;k++){
            float v_ = slab[k*256+px]*inv;
            asm volatile("" : "+v"(v_));     // forbid LDS rematerialization
            wf[q][k] = v_;
        }
    }

    // per-lane byte offsets into a source channel plane (edge-clamped)
    int voff[25];
    #pragma unroll
    for (int dr=0;dr<5;dr++){
        int sr_ = m - 2 + dr; sr_ = sr_ < 0 ? 0 : (sr_ > SH-1 ? SH-1 : sr_);
        #pragma unroll
        for (int dc=0;dc<5;dc++){
            int sc_ = n - 2 + dc; sc_ = sc_ < 0 ? 0 : (sc_ > SW-1 ? SW-1 : sc_);
            voff[dr*5+dc] = (sr_*SW + sc_)*4;
        }
    }
    const int ooffB = ((2*m)*GW + 2*n)*4;

    const int wid_u = __builtin_amdgcn_readfirstlane(wid);  // SGPR base chains

    for (int it = 0; it < CPB/4; ++it){
        int c = cb*CPB + wid_u + it*4;
        const char* sb = (const char*)(src + (size_t)(b*SC + c)*HWs);
        float v[25];
        #pragma unroll
        for (int k=0;k<25;k++) v[k] = *(const float*)(sb + voff[k]);
        float a0=0.f, a1=0.f, a2=0.f, a3=0.f;
        #pragma unroll
        for (int k=0;k<25;k++){
            a0 += wf[0][k]*v[k];
            a1 += wf[1][k]*v[k];
            a2 += wf[2][k]*v[k];
            a3 += wf[3][k]*v[k];
        }
        char* ob = (char*)(out + (size_t)(b*SC + c)*HWg) + ooffB;
        f32x2 r0 = {a0, a1};
        f32x2 r1 = {a2, a3};
        __builtin_nontemporal_store(r0, (f32x2*)ob);
        __builtin_nontemporal_store(r1, (f32x2*)(ob + GW*4));
    }
}

extern "C" void kernel_launch(void* const* d_in, const int* in_sizes, int n_in,
                              void* d_out, int out_size, void* d_ws, size_t ws_size,
                              hipStream_t stream) {
    (void)in_sizes; (void)n_in; (void)d_ws; (void)ws_size; (void)out_size;
    const float* src  = (const float*)d_in[0];
    const float* gdn  = (const float*)d_in[1];
    const float* sigs = (const float*)d_in[2];
    const float* sigr = (const float*)d_in[3];
    float* out = (float*)d_out;

    dim3 grid(NCB * BB * 196);   // 784 blocks
    dim3 block(256);
    jbu_kernel<<<grid, block, 0, stream>>>(src, gdn, sigs, sigr, out);
}

// Round 6
// 274.330 us; speedup vs baseline: 1.2338x; 1.2338x over previous
//
#include <hip/hip_runtime.h>
#include <math.h>
#include <stdint.h>

#define BB   2
#define SC   384
#define SH   112
#define SW   112
#define GH   224
#define GW   224
#define HWs  (SH*SW)     // 12544
#define HWg  (GH*GW)     // 50176
#define GT   22          // 16 + 2*3 guidance tile dim
#define NCB  2           // channel blocks
#define CPB  (SC/NCB)    // 192 channels per block
#define NIT  (CPB/4)     // 48 channel iterations per wave

typedef float f32x2 __attribute__((ext_vector_type(2)));
typedef __attribute__((address_space(3))) uint32_t lds_u32_t;
typedef const __attribute__((address_space(1))) uint32_t glb_u32_t;

__device__ __forceinline__ int reflect224(int v){
    v = v < 0 ? -v : v;
    v = v > 223 ? 446 - v : v;
    return v;
}

// slab column permutation: pixel t=(hh*16+ww), hh=2*wm+e, ww=2*wn+f.
// col = e<<7 | f<<6 | wm<<3 | wn  -> phase-1 writes AND wf read-back are
// both exact 2-way bank patterns (free). Old layout made read-back 8-way.
__device__ __forceinline__ int slabcol(int t){
    int wm = t >> 5, e = (t >> 4) & 1, wn = (t >> 1) & 7, f = t & 1;
    return (e << 7) | (f << 6) | (wm << 3) | wn;
}

__launch_bounds__(256, 2)
__global__ void jbu_kernel(const float* __restrict__ src,
                           const float* __restrict__ gdn,
                           const float* __restrict__ sigs,
                           const float* __restrict__ sigr,
                           float* __restrict__ out)
{
    // LDS: 5808 + 25600 + 1024 + 6144 = 38576 B
    __shared__ float gtile[GT*GT*3];
    __shared__ float slab[25*256];
    __shared__ float invs_sh[256];
    __shared__ float lds_stage[4][2][192];   // per-wave double buffer, 12x12 (+pad)

    const int bx = blockIdx.x;
    const int cb = bx / 392;
    const int r  = bx - cb*392;
    const int b  = r / 196;
    const int t  = r - b*196;
    const int th = t / 14, tw = t - th*14;
    const int h0 = th*16, w0 = tw*16;

    const int tid = threadIdx.x;

    const float ssv  = fabsf(sigs[0]);
    const float srv  = fabsf(sigr[0]);
    const float i2ss = 0.5f/(ssv*ssv);
    const float i2sr = 0.5f/(srv*srv);

    const int mycol = slabcol(tid);
    #pragma unroll
    for (int k=0;k<25;k++) slab[k*256+mycol] = 0.f;

    // stage L2-normalized guidance tile, reflect applied at staging
    const float* gb = gdn + (size_t)b*3*HWg;
    for (int idx = tid; idx < GT*GT; idx += 256){
        int ty = idx / GT, tx = idx - ty*GT;
        int y = reflect224(h0 - 3 + ty);
        int x = reflect224(w0 - 3 + tx);
        float g0 = gb[y*GW + x];
        float g1 = gb[HWg   + y*GW + x];
        float g2 = gb[2*HWg + y*GW + x];
        float nrm = sqrtf(g0*g0 + g1*g1 + g2*g2);
        float inv = 1.0f / fmaxf(nrm, 1e-12f);
        gtile[idx*3+0] = g0*inv;
        gtile[idx*3+1] = g1*inv;
        gtile[idx*3+2] = g2*inv;
    }
    __syncthreads();

    // ---- phase 1: per-pixel effective 5x5 source weights ----
    const int hh = tid >> 4, ww = tid & 15;
    const int h = h0 + hh, w = w0 + ww;
    const float c0 = gtile[((hh+3)*GT + (ww+3))*3 + 0];
    const float c1 = gtile[((hh+3)*GT + (ww+3))*3 + 1];
    const float c2 = gtile[((hh+3)*GT + (ww+3))*3 + 2];

    float wc0a[7]; int dc0a[7];
    #pragma unroll
    for (int j=0;j<7;j++){
        int xr = reflect224(w + j - 3);
        int a  = xr >> 1;
        int cs0 = a - 1 + (xr & 1);
        wc0a[j] = (xr & 1) ? 0.75f : 0.25f;
        dc0a[j] = cs0 - ((w>>1) - 2);
    }

    float sum = 0.f;
    #pragma unroll
    for (int i=0;i<7;i++){
        int yr = reflect224(h + i - 3);
        int a  = yr >> 1;
        int rs0 = a - 1 + (yr & 1);
        float wr0 = (yr & 1) ? 0.75f : 0.25f;
        int dr0 = rs0 - ((h>>1) - 2);
        const float* grow = &gtile[((hh+i)*GT + ww)*3];
        float di2 = (float)((i-3)*(i-3));
        #pragma unroll
        for (int j=0;j<7;j++){
            float dot = c0*grow[j*3+0] + c1*grow[j*3+1] + c2*grow[j*3+2];
            float t2  = 2.0f - dot;
            float dj2 = (float)((j-3)*(j-3));
            float ck  = __expf(-(t2*t2*i2sr + (di2+dj2)*i2ss));
            sum += ck;
            float p0 = ck*wr0, p1 = ck - p0;
            float wc0 = wc0a[j];
            float q00 = p0*wc0, q01 = p0 - q00;
            float q10 = p1*wc0, q11 = p1 - q10;
            int base = (dr0*5 + dc0a[j])*256 + mycol;
            slab[base        ] += q00;
            slab[base +   256] += q01;
            slab[base + 5*256] += q10;
            slab[base + 6*256] += q11;
        }
    }
    invs_sh[tid] = 1.0f / fmaxf(sum, 1e-7f);
    __syncthreads();

    // ---- phase 2: adaptive 5x5 conv, LDS-staged source windows ----
    const int wid  = tid >> 6, lane = tid & 63;
    const int wm   = lane >> 3, wn = lane & 7;
    const int m    = th*8 + wm, n = tw*8 + wn;

    // wf -> registers. volatile: compiler may spill (AGPR/scratch) but can
    // NEVER re-read slab inside the channel loop (round-4/5 lesson).
    float wf[4][25];
    #pragma unroll
    for (int q=0;q<4;q++){
        const int e = q>>1, f = q&1;
        const int px  = (2*wm+e)*16 + (2*wn+f);
        const int col = (e<<7) | (f<<6) | (wm<<3) | wn;   // slabcol(px)
        const float inv = invs_sh[px];
        volatile const float* vs = &slab[col];
        #pragma unroll
        for (int k=0;k<25;k++){
            float v_ = vs[k*256]*inv;
            asm volatile("" : "+v"(v_));
            wf[q][k] = v_;
        }
    }

    // per-lane staging source byte offsets (12x12 clamped window, 3 chunks)
    int soff[3];
    #pragma unroll
    for (int k2=0;k2<3;k2++){
        int l = k2*64 + lane; if (l > 143) l = 143;   // pad lanes: dummy
        int rr_ = th*8 - 2 + l/12;
        int cc_ = tw*8 - 2 + l%12;
        rr_ = rr_ < 0 ? 0 : (rr_ > SH-1 ? SH-1 : rr_);
        cc_ = cc_ < 0 ? 0 : (cc_ > SW-1 ? SW-1 : cc_);
        soff[k2] = (rr_*SW + cc_)*4;
    }

    const int ooffB = ((2*m)*GW + 2*n)*4;
    const int wid_u = __builtin_amdgcn_readfirstlane(wid);
    const char* sp0 = (const char*)(src + (size_t)(b*SC + cb*CPB + wid_u)*HWs);
    char*       op0 = (char*)(out + (size_t)(b*SC + cb*CPB + wid_u)*HWg) + ooffB;
    float* buf0 = &lds_stage[wid_u][0][0];
    float* buf1 = &lds_stage[wid_u][1][0];

    // global_load_lds: dest = wave-uniform LDS base + lane*4 (HW rule);
    // source is per-lane. 3 chunks fill 144 floats (+48 pad).
#define STAGE(BUFP, ITC) do { \
        const char* _g = sp0 + (size_t)(ITC)*(4*HWs*4); \
        lds_u32_t* _l = (lds_u32_t*)(BUFP); \
        __builtin_amdgcn_global_load_lds((glb_u32_t*)(_g + soff[0]), _l      , 4, 0, 0); \
        __builtin_amdgcn_global_load_lds((glb_u32_t*)(_g + soff[1]), _l +  64, 4, 0, 0); \
        __builtin_amdgcn_global_load_lds((glb_u32_t*)(_g + soff[2]), _l + 128, 4, 0, 0); \
    } while(0)

    // Per-iter: wait buf loads (counted vmcnt; stores also occupy the queue:
    // steady state = 2 stores + 3 loads + 2 stores newer => vmcnt(7)),
    // read 25 window values (stride-12 rows: exact 2-way banks, free),
    // lgkmcnt(0), then overwrite-prefetch ch+2 into the same buffer.
#define ITER(IT, VM, CBUF, DO_PF) do { \
        asm volatile("s_waitcnt vmcnt(" #VM ")" ::: "memory"); \
        __builtin_amdgcn_sched_barrier(0); \
        const float* _bp = (CBUF) + wm*12 + wn; \
        float vv[25]; \
        _Pragma("unroll") \
        for (int dr=0;dr<5;dr++){ \
            _Pragma("unroll") \
            for (int dc=0;dc<5;dc++) vv[dr*5+dc] = _bp[dr*12+dc]; \
        } \
        asm volatile("s_waitcnt lgkmcnt(0)" ::: "memory"); \
        __builtin_amdgcn_sched_barrier(0); \
        if (DO_PF) STAGE(CBUF, (IT)+2); \
        float a0=0.f,a1=0.f,a2=0.f,a3=0.f; \
        _Pragma("unroll") \
        for (int k=0;k<25;k++){ \
            a0 += wf[0][k]*vv[k]; \
            a1 += wf[1][k]*vv[k]; \
            a2 += wf[2][k]*vv[k]; \
            a3 += wf[3][k]*vv[k]; \
        } \
        char* _ob = op0 + (size_t)(IT)*(4*HWg*4); \
        f32x2 _r0 = {a0,a1}, _r1 = {a2,a3}; \
        __builtin_nontemporal_store(_r0, (f32x2*)_ob); \
        __builtin_nontemporal_store(_r1, (f32x2*)(_ob + GW*4)); \
    } while(0)

    STAGE(buf0, 0);
    STAGE(buf1, 1);
    ITER(0, 3, buf0, true);
    ITER(1, 5, buf1, true);
    for (int it2 = 2; it2 < NIT-2; it2 += 2){
        ITER(it2,   7, buf0, true);
        ITER(it2+1, 7, buf1, true);
    }
    ITER(NIT-2, 7, buf0, false);
    ITER(NIT-1, 4, buf1, false);

#undef ITER
#undef STAGE
}

extern "C" void kernel_launch(void* const* d_in, const int* in_sizes, int n_in,
                              void* d_out, int out_size, void* d_ws, size_t ws_size,
                              hipStream_t stream) {
    (void)in_sizes; (void)n_in; (void)d_ws; (void)ws_size; (void)out_size;
    const float* src  = (const float*)d_in[0];
    const float* gdn  = (const float*)d_in[1];
    const float* sigs = (const float*)d_in[2];
    const float* sigr = (const float*)d_in[3];
    float* out = (float*)d_out;

    dim3 grid(NCB * BB * 196);   // 784 blocks
    dim3 block(256);
    jbu_kernel<<<grid, block, 0, stream>>>(src, gdn, sigs, sigr, out);
}